// Round 17
// baseline (101.418 us; speedup 1.0000x reference)
//
#include <hip/hip_runtime.h>
#include <hip/hip_bf16.h>

// LocalKNN: B=64, Way=5, D=64, Nq=1024, Ns=1024, K=3.
// out[b,w] = sum_q rnq[q] * sum(top3_s( <q_bq, shat_bws> ))
// Round 17: 32x32x16 MFMA. One q-tile (32 q) per wave; c[16]/lane gives a
// 16-wide INS stream; 4x fewer MFMA issues at a 15% higher pipe rate; t-state
// 6 regs. Barrier-free private 2-slot rings (32KB/block -> 5 blocks/CU),
// vmcnt(4) pacing, ds_read -> lgkmcnt(0)+sched_barrier -> STAGE slot reuse,
// dual c-sets by tile parity, waves_per_eu(5,8).
// A/B fragments use the SAME (lane,reg)->k mapping, so the contraction is
// correct regardless of the HW's internal k pairing.

using bf16x8 = __attribute__((ext_vector_type(8))) short;   // 8 bf16 = 4 VGPRs
using f32x4  = __attribute__((ext_vector_type(4))) float;
using f32x16 = __attribute__((ext_vector_type(16))) float;

__device__ inline unsigned cvt_pk_bf16(float lo, float hi) {
    unsigned r;
    asm("v_cvt_pk_bf16_f32 %0, %1, %2" : "=v"(r) : "v"(lo), "v"(hi));
    return r;
}

__device__ inline uint4 pack8cvt(const float* v) {
    uint4 r;
    r.x = cvt_pk_bf16(v[0], v[1]);
    r.y = cvt_pk_bf16(v[2], v[3]);
    r.z = cvt_pk_bf16(v[4], v[5]);
    r.w = cvt_pk_bf16(v[6], v[7]);
    return r;
}

// branchless insert of v into sorted top-3 (t0>=t1>=t2): 1 max + 2 med3
#define INS(v, T0, T1, T2) do {                         \
    float _v = (v);                                     \
    float _n0 = fmaxf((T0), _v);                        \
    float _n1 = __builtin_amdgcn_fmed3f(_v, (T0), (T1));\
    float _n2 = __builtin_amdgcn_fmed3f(_v, (T1), (T2));\
    (T0) = _n0; (T1) = _n1; (T2) = _n2;                 \
} while (0)

// async 16B/lane global->LDS (LDS dest = wave-uniform base + lane*16)
__device__ inline void gload16(const void* g, void* lds) {
    __builtin_amdgcn_global_load_lds(
        (const __attribute__((address_space(1))) unsigned int*)g,
        (__attribute__((address_space(3))) unsigned int*)lds,
        16, 0, 0);
}

// ============================= fast path =====================================
// 32-col tile layout (4 KB per tile = 256 uint4): slot = kb*64 + half*32 +
// (col&31) holds column col's elements k = 16*kb + 8*half + j (j=0..7) packed
// bf16. MFMA read: lane l, reg j -> (col = l&31, k = 16*kb + 8*(l>>5) + j).
// A (S) and B (Q) use this identical mapping.

// ---- prep_all: raw Q/S -> bf16 32-tile fragments (+ rnq) --------------------
__global__ __launch_bounds__(256) void prep_all(const float* __restrict__ Q,
                                                const float* __restrict__ S,
                                                uint4* __restrict__ Qbf,
                                                uint4* __restrict__ Sbf,
                                                float* __restrict__ rnq) {
    const int blk = blockIdx.x;
    if (blk < 256) {
        const int b = blk >> 2;
        const int col = ((blk & 3) << 8) + threadIdx.x;      // q in 0..1023
        const float* p = Q + (size_t)b * 65536 + col;
        float v[64];
        #pragma unroll
        for (int d = 0; d < 64; ++d) v[d] = p[(size_t)d << 10];
        float ss = 0.f;
        #pragma unroll
        for (int d = 0; d < 64; ++d) ss += v[d] * v[d];
        rnq[(b << 10) + col] = 1.0f / fmaxf(sqrtf(ss), 1e-12f);
        uint4* ob = Qbf + (size_t)b * 8192 + (size_t)(col >> 5) * 256 + (col & 31);
        #pragma unroll
        for (int kb = 0; kb < 4; ++kb)
            #pragma unroll
            for (int hf = 0; hf < 2; ++hf)
                ob[kb * 64 + hf * 32] = pack8cvt(&v[kb * 16 + hf * 8]);
    } else {
        const int bw = (blk - 256) >> 2;
        const int col = ((blk & 3) << 8) + threadIdx.x;      // s in 0..1023
        const float* p = S + (size_t)bw * 65536 + col;
        float v[64];
        #pragma unroll
        for (int d = 0; d < 64; ++d) v[d] = p[(size_t)d << 10];
        float ss = 0.f;
        #pragma unroll
        for (int d = 0; d < 64; ++d) ss += v[d] * v[d];
        const float rs = 1.0f / fmaxf(sqrtf(ss), 1e-12f);
        #pragma unroll
        for (int d = 0; d < 64; ++d) v[d] *= rs;
        uint4* ob = Sbf + (size_t)bw * 8192 + (size_t)(col >> 5) * 256 + (col & 31);
        #pragma unroll
        for (int kb = 0; kb < 4; ++kb)
            #pragma unroll
            for (int hf = 0; hf < 2; ++hf)
                ob[kb * 64 + hf * 32] = pack8cvt(&v[kb * 16 + hf * 8]);
    }
}

// ---- main: 32x32 MFMA, barrier-free per-wave double-buffer ------------------
// grid 2560 (logical l: qg = l&7, bw = l>>3), block 256 = 4 waves.
// Wave wv owns q-tile qg*4+wv (32 q) and streams all 32 s-tiles of (b,w).
__global__ __launch_bounds__(256)
__attribute__((amdgpu_waves_per_eu(5, 8)))
void knn_main(const uint4* __restrict__ Qbf,
              const uint4* __restrict__ Sbf,
              const float* __restrict__ rnq,
              float* __restrict__ partial) {
    __shared__ uint4 ring[4][2 * 256];   // per wave: 2 slots x 4 KB; total 32 KB
    const int lin = blockIdx.x;
    const int l   = (lin & 7) * 320 + (lin >> 3);   // 2560 = 8*320, bijective
    const int qg  = l & 7;
    const int bw  = l >> 3;                          // b*5 + w
    const int b   = bw / 5;
    const int wv = threadIdx.x >> 6, lane = threadIdx.x & 63;

    // B fragments: q-tile qg*4+wv, 4 k-blocks
    const uint4* qb = Qbf + (size_t)b * 8192 + (size_t)(qg * 4 + wv) * 256 + lane;
    bf16x8 bq[4];
    #pragma unroll
    for (int kb = 0; kb < 4; ++kb)
        bq[kb] = *reinterpret_cast<const bf16x8*>(&qb[kb * 64]);

    const char* sbyte = (const char*)(Sbf + (size_t)bw * 8192) + (size_t)lane * 16;
    uint4* myring = &ring[wv][0];

    float tA0 = -1e30f, tA1 = -1e30f, tA2 = -1e30f;
    float tB0 = -1e30f, tB1 = -1e30f, tB2 = -1e30f;
    f32x16 cA, cB;
    const f32x16 z16 = {0.f,0.f,0.f,0.f,0.f,0.f,0.f,0.f,
                        0.f,0.f,0.f,0.f,0.f,0.f,0.f,0.f};

    auto STAGE = [&](int tile, int slot) {
        #pragma unroll
        for (int kb = 0; kb < 4; ++kb)
            gload16(sbyte + (size_t)tile * 4096 + kb * 1024,
                    &myring[slot * 256 + kb * 64]);
    };

    // prologue: stage tiles 0,1
    STAGE(0, 0);
    STAGE(1, 1);

    // main loop, fully unrolled; slot = t&1; dual c-sets by parity
    #pragma unroll
    for (int t = 0; t < 32; ++t) {
        if (t < 30)      { asm volatile("s_waitcnt vmcnt(4)" ::: "memory"); }
        else if (t == 30){ asm volatile("s_waitcnt vmcnt(4)" ::: "memory"); }
        else             { asm volatile("s_waitcnt vmcnt(0)" ::: "memory"); }
        const uint4* sp = &myring[(t & 1) * 256];
        bf16x8 a0 = *reinterpret_cast<const bf16x8*>(&sp[0 * 64 + lane]);
        bf16x8 a1 = *reinterpret_cast<const bf16x8*>(&sp[1 * 64 + lane]);
        bf16x8 a2 = *reinterpret_cast<const bf16x8*>(&sp[2 * 64 + lane]);
        bf16x8 a3 = *reinterpret_cast<const bf16x8*>(&sp[3 * 64 + lane]);
        asm volatile("s_waitcnt lgkmcnt(0)" ::: "memory");
        __builtin_amdgcn_sched_barrier(0);
        if (t < 30) STAGE(t + 2, t & 1);      // safe: reads of this slot done
        if ((t & 1) == 0) {
            cA = __builtin_amdgcn_mfma_f32_32x32x16_bf16(a0, bq[0], z16, 0, 0, 0);
            cA = __builtin_amdgcn_mfma_f32_32x32x16_bf16(a1, bq[1], cA, 0, 0, 0);
            cA = __builtin_amdgcn_mfma_f32_32x32x16_bf16(a2, bq[2], cA, 0, 0, 0);
            cA = __builtin_amdgcn_mfma_f32_32x32x16_bf16(a3, bq[3], cA, 0, 0, 0);
            if (t > 0) {
                #pragma unroll
                for (int j = 0; j < 16; ++j) INS(cB[j], tB0, tB1, tB2);
            }
        } else {
            cB = __builtin_amdgcn_mfma_f32_32x32x16_bf16(a0, bq[0], z16, 0, 0, 0);
            cB = __builtin_amdgcn_mfma_f32_32x32x16_bf16(a1, bq[1], cB, 0, 0, 0);
            cB = __builtin_amdgcn_mfma_f32_32x32x16_bf16(a2, bq[2], cB, 0, 0, 0);
            cB = __builtin_amdgcn_mfma_f32_32x32x16_bf16(a3, bq[3], cB, 0, 0, 0);
            #pragma unroll
            for (int j = 0; j < 16; ++j) INS(cA[j], tA0, tA1, tA2);
        }
    }
    // drain last two accumulators (tile 30 -> cA, tile 31 -> cB)
    #pragma unroll
    for (int j = 0; j < 16; ++j) INS(cA[j], tA0, tA1, tA2);
    #pragma unroll
    for (int j = 0; j < 16; ++j) INS(cB[j], tB0, tB1, tB2);

    // merge B-set into A-set
    INS(tB0, tA0, tA1, tA2);
    INS(tB1, tA0, tA1, tA2);
    INS(tB2, tA0, tA1, tA2);
    // merge the two lane-halves sharing each q (lane ^ 32)
    {
        float b0 = __shfl_xor(tA0, 32);
        float b1 = __shfl_xor(tA1, 32);
        float b2 = __shfl_xor(tA2, 32);
        INS(b0, tA0, tA1, tA2);
        INS(b1, tA0, tA1, tA2);
        INS(b2, tA0, tA1, tA2);
    }
    // per-lane q = (qg*4+wv)*32 + (lane&31); apply rnq; sum over q
    const int q = ((qg * 4 + wv) << 5) + (lane & 31);
    float s3 = (tA0 + tA1 + tA2) * rnq[(b << 10) + q];
    #pragma unroll
    for (int m = 1; m < 64; m <<= 1) s3 += __shfl_xor(s3, m);
    s3 *= 0.5f;                         // each q counted by 2 lane-halves
    if (lane == 0) partial[(size_t)bw * 32 + qg * 4 + wv] = s3;
}

__global__ void finalize32(const float* __restrict__ partial, float* __restrict__ out) {
    int i = blockIdx.x * blockDim.x + threadIdx.x;
    if (i < 320) {
        float a = 0.f;
        #pragma unroll
        for (int k = 0; k < 32; ++k) a += partial[32 * i + k];
        out[i] = a;
    }
}

// ============================ fallback path (round-2) ========================
__global__ void norms_kernel(const float* __restrict__ Q, const float* __restrict__ S,
                             float* __restrict__ rnq, float* __restrict__ rns) {
    int gid = blockIdx.x * blockDim.x + threadIdx.x;
    if (gid < 65536) {
        int b = gid >> 10, qi = gid & 1023;
        const float* p = Q + (size_t)b * 65536 + qi;
        float ss = 0.f;
        #pragma unroll
        for (int d = 0; d < 64; ++d) { float v = p[(size_t)d * 1024]; ss += v * v; }
        rnq[gid] = 1.0f / fmaxf(sqrtf(ss), 1e-12f);
    } else {
        int v = gid - 65536;
        int bw = v >> 10, si = v & 1023;
        const float* p = S + (size_t)bw * 65536 + si;
        float ss = 0.f;
        #pragma unroll
        for (int d = 0; d < 64; ++d) { float x = p[(size_t)d * 1024]; ss += x * x; }
        rns[v] = 1.0f / fmaxf(sqrtf(ss), 1e-12f);
    }
}

__global__ __launch_bounds__(512, 4) void knn_fb(
        const float* __restrict__ Q, const float* __restrict__ S,
        const float* __restrict__ rnq, const float* __restrict__ rns,
        float* __restrict__ partial) {
    __shared__ uint4 qfrag[16 * 128];
    __shared__ uint4 sfrag[2][4 * 128];
    __shared__ float wsum[8];

    const int qc = blockIdx.x, w = blockIdx.y, b = blockIdx.z;
    const int t = threadIdx.x, wv = t >> 6, lane = t & 63;

    const float* Qb   = Q + (size_t)b * 65536;
    const float* Sb   = S + (size_t)(b * 5 + w) * 65536;
    const float* rnqb = rnq + (b << 10);
    const float* rnsb = rns + ((b * 5 + w) << 10);

    bf16x8 bq[4][2];
    for (int ph = 0; ph < 2; ++ph) {
        for (int sub = 0; sub < 4; ++sub) {
            int qg = (qc << 9) + (ph << 8) + (sub << 6) + lane;
            float v[8];
            #pragma unroll
            for (int i = 0; i < 8; ++i)
                v[i] = Qb[(size_t)((wv << 3) + i) * 1024 + qg];
            qfrag[((sub << 2) + (lane >> 4)) * 128 + (wv << 4) + (lane & 15)] = pack8cvt(v);
        }
        __syncthreads();
        if ((wv >> 2) == ph) {
            #pragma unroll
            for (int qt = 0; qt < 4; ++qt)
                #pragma unroll
                for (int c = 0; c < 2; ++c)
                    bq[qt][c] = *reinterpret_cast<const bf16x8*>(
                        &qfrag[(((wv & 3) << 2) + qt) * 128 + (c << 6) + lane]);
        }
        __syncthreads();
    }

    {
        float sv[8]; float rs = rnsb[lane];
        #pragma unroll
        for (int i = 0; i < 8; ++i)
            sv[i] = Sb[(size_t)((wv << 3) + i) * 1024 + lane] * rs;
        sfrag[0][(lane >> 4) * 128 + (wv << 4) + (lane & 15)] = pack8cvt(sv);
    }
    __syncthreads();

    float t0[4], t1[4], t2[4];
    #pragma unroll
    for (int qt = 0; qt < 4; ++qt) { t0[qt] = -1e30f; t1[qt] = -1e30f; t2[qt] = -1e30f; }
    int cur = 0;
    const float* sp = Sb + ((wv << 3) << 10) + lane;

    for (int blk = 0; blk < 16; ++blk) {
        float sv[8]; float rs;
        if (blk < 15) {
            const int sb_ = (blk + 1) << 6;
            rs = rnsb[sb_ + lane];
            #pragma unroll
            for (int i = 0; i < 8; ++i)
                sv[i] = sp[(size_t)(i << 10) + sb_];
        }
        #pragma unroll
        for (int st = 0; st < 4; ++st) {
            bf16x8 a0 = *reinterpret_cast<const bf16x8*>(&sfrag[cur][st * 128 + lane]);
            bf16x8 a1 = *reinterpret_cast<const bf16x8*>(&sfrag[cur][st * 128 + 64 + lane]);
            #pragma unroll
            for (int qt = 0; qt < 4; ++qt) {
                f32x4 c = {0.f, 0.f, 0.f, 0.f};
                c = __builtin_amdgcn_mfma_f32_16x16x32_bf16(a0, bq[qt][0], c, 0, 0, 0);
                c = __builtin_amdgcn_mfma_f32_16x16x32_bf16(a1, bq[qt][1], c, 0, 0, 0);
                #pragma unroll
                for (int j = 0; j < 4; ++j)
                    INS(c[j], t0[qt], t1[qt], t2[qt]);
            }
        }
        if (blk < 15) {
            #pragma unroll
            for (int i = 0; i < 8; ++i) sv[i] *= rs;
            sfrag[cur ^ 1][(lane >> 4) * 128 + (wv << 4) + (lane & 15)] = pack8cvt(sv);
        }
        __syncthreads();
        cur ^= 1;
    }

    float s3 = 0.f;
    #pragma unroll
    for (int qt = 0; qt < 4; ++qt) {
        #pragma unroll
        for (int m = 16; m <= 32; m <<= 1) {
            float b0 = __shfl_xor(t0[qt], m);
            float b1 = __shfl_xor(t1[qt], m);
            float b2 = __shfl_xor(t2[qt], m);
            INS(b0, t0[qt], t1[qt], t2[qt]);
            INS(b1, t0[qt], t1[qt], t2[qt]);
            INS(b2, t0[qt], t1[qt], t2[qt]);
        }
        int qg = (qc << 9) + (wv << 6) + (qt << 4) + (lane & 15);
        s3 += (t0[qt] + t1[qt] + t2[qt]) * rnqb[qg];
    }
    #pragma unroll
    for (int m = 1; m < 64; m <<= 1) s3 += __shfl_xor(s3, m);
    s3 *= 0.25f;
    if (lane == 0) wsum[wv] = s3;
    __syncthreads();
    if (t == 0) {
        float acc = 0.f;
        #pragma unroll
        for (int i = 0; i < 8; ++i) acc += wsum[i];
        partial[((b * 5 + w) << 1) + qc] = acc;
    }
}

__global__ void finalize2(const float* __restrict__ partial, float* __restrict__ out) {
    int i = blockIdx.x * blockDim.x + threadIdx.x;
    if (i < 320)
        out[i] = partial[2 * i] + partial[2 * i + 1];
}

// =============================================================================
extern "C" void kernel_launch(void* const* d_in, const int* in_sizes, int n_in,
                              void* d_out, int out_size, void* d_ws, size_t ws_size,
                              hipStream_t stream) {
    const float* Q = (const float*)d_in[0];   // (64,64,32,32)
    const float* S = (const float*)d_in[1];   // (64,5,64,1024)
    float* out = (float*)d_out;               // (64,5)

    // fast-path ws: Qbf 8 MB | Sbf 41.9 MB | rnq 256 KB | partial 40 KB
    const size_t QBF = 8388608ull, SBF = 41943040ull, RNQ = 262144ull;
    const size_t NEED = QBF + SBF + RNQ + 40960ull;
    if (ws_size >= NEED) {
        char* base = (char*)d_ws;
        uint4* Qbf     = (uint4*)base;
        uint4* Sbf     = (uint4*)(base + QBF);
        float* rnq     = (float*)(base + QBF + SBF);
        float* partial = (float*)(base + QBF + SBF + RNQ);
        prep_all<<<1536, 256, 0, stream>>>(Q, S, Qbf, Sbf, rnq);
        knn_main<<<2560, 256, 0, stream>>>(Qbf, Sbf, rnq, partial);
        finalize32<<<2, 256, 0, stream>>>(partial, out);
    } else {
        float* rnq = (float*)d_ws;
        float* rns = rnq + 65536;
        float* partial = rns + 327680;
        norms_kernel<<<(65536 + 327680) / 256, 256, 0, stream>>>(Q, S, rnq, rns);
        knn_fb<<<dim3(2, 5, 64), 512, 0, stream>>>(Q, S, rnq, rns, partial);
        finalize2<<<2, 256, 0, stream>>>(partial, out);
    }
}